// Round 1
// baseline (3998.617 us; speedup 1.0000x reference)
//
#include <hip/hip_runtime.h>
#include <math.h>
#include <algorithm>

#define NATOM 20000
#define NEIGH 600000
#define NWAVE 8
#define NSPH 16
// sum_sph layout: [atom][k(16)][w(8)] -> atom*128 + k*8 + w

struct W3JT {
  int cnt[6];
  int k1[6][32];
  int k2[6][32];
  int k3[6][32];
  float cf[6][32];
};

__device__ __forceinline__ float silu_f(float x) { return x / (1.f + expf(-x)); }

// ---------------- Kernel 1: per-atom embedding MLP ----------------
__global__ __launch_bounds__(256) void emb_kernel(
    const float* __restrict__ species,
    const float* __restrict__ W1, const float* __restrict__ b1,
    const float* __restrict__ W2, const float* __restrict__ b2,
    const float* __restrict__ W3, const float* __restrict__ b3,
    float* __restrict__ emb)
{
  int a = blockIdx.x * 256 + threadIdx.x;
  if (a >= NATOM) return;
  float spv = species[a];
  float h1[16], h2[16];
#pragma unroll
  for (int c = 0; c < 16; ++c) {
    float v = spv * W1[c] + b1[c];
    h1[c] = silu_f(v);
  }
#pragma unroll
  for (int d = 0; d < 16; ++d) {
    float v = b2[d];
#pragma unroll
    for (int c = 0; c < 16; ++c) v += h1[c] * W2[c * 16 + d];
    h2[d] = silu_f(v);
  }
#pragma unroll
  for (int e = 0; e < 24; ++e) {
    float v = b3[e];
#pragma unroll
    for (int c = 0; c < 16; ++c) v += h2[c] * W3[c * 24 + e];
    emb[a * 24 + e] = v;
  }
}

// ---------------- Kernel 2: per-neighbor equivariant scatter ----------------
__global__ __launch_bounds__(256) void neigh_kernel(
    const float* __restrict__ cart, const int* __restrict__ aidx,
    const float* __restrict__ shifts, const float* __restrict__ emb,
    float* __restrict__ sum_sph)
{
  int n = blockIdx.x * 256 + threadIdx.x;
  if (n >= NEIGH) return;
  int i = aidx[n];
  int j = aidx[NEIGH + n];
  float cx = cart[j]             - cart[i]             + shifts[n];
  float cy = cart[NATOM + j]     - cart[NATOM + i]     + shifts[NEIGH + n];
  float cz = cart[2 * NATOM + j] - cart[2 * NATOM + i] + shifts[2 * NEIGH + n];
  float dist = sqrtf(cx * cx + cy * cy + cz * cz);
  float inv = 1.f / dist;
  float x = cx * inv, y = cy * inv, z = cz * inv;

  // cutoff: ((cos(d/5*pi)+1)/2)^3  -- no clamp, matching reference
  float cc = cosf(dist * 0.62831853071795864769f);
  float cut0 = (cc + 1.f) * 0.5f;
  float cut = cut0 * cut0 * cut0;

  // radial * coeff per wave
  const float* e = emb + j * 24;
  float aw[NWAVE];
#pragma unroll
  for (int w = 0; w < NWAVE; ++w) {
    float coeff = e[w], alpha = e[8 + w], center = e[16 + w];
    float sd = alpha * (dist - center);
    aw[w] = cut * coeff * expf(-sd * sd);
  }

  // real spherical harmonics, l<=3 (same recurrences as reference)
  float sz = sqrtf(fmaxf(1.f - z * z, 0.f));
  float rxy = sqrtf(x * x + y * y);
  float cp, sp;
  if (rxy > 0.f) { float ri = 1.f / rxy; cp = x * ri; sp = y * ri; }
  else           { cp = 1.f; sp = 0.f; }
  float c2 = cp * cp - sp * sp, s2 = 2.f * cp * sp;
  float c3 = c2 * cp - s2 * sp, s3 = s2 * cp + c2 * sp;

  float P11 = -sz;
  float P22 = -3.f * sz * P11;
  float P33 = -5.f * sz * P22;
  float P10 = z;
  float P21 = 3.f * z * P11;
  float P32 = 5.f * z * P22;
  float P20 = (3.f * z * P10 - 1.f) * 0.5f;
  float P31 = (5.f * z * P21 - 3.f * P11) * 0.5f;
  float P30 = (5.f * z * P20 - 2.f * P10) * (1.f / 3.f);

  const float SQ2 = 1.41421356237309515f;
  float sph[NSPH];
  sph[0]  = 0.28209479177387814f;
  sph[1]  = SQ2 * 0.3454941494713355f  * sp * P11;
  sph[2]  = 0.4886025119029199f * P10;
  sph[3]  = SQ2 * 0.3454941494713355f  * cp * P11;
  sph[4]  = SQ2 * 0.12875806734106326f * s2 * P22;
  sph[5]  = SQ2 * 0.25751613468212653f * sp * P21;
  sph[6]  = 0.6307831305050401f * P20;
  sph[7]  = SQ2 * 0.25751613468212653f * cp * P21;
  sph[8]  = SQ2 * 0.12875806734106326f * c2 * P22;
  sph[9]  = SQ2 * 0.027814921575518937f * s3 * P33;
  sph[10] = SQ2 * 0.06813236509555433f  * s2 * P32;
  sph[11] = SQ2 * 0.2154534560761003f   * sp * P31;
  sph[12] = 0.7463526651802308f * P30;
  sph[13] = SQ2 * 0.2154534560761003f   * cp * P31;
  sph[14] = SQ2 * 0.06813236509555433f  * c2 * P32;
  sph[15] = SQ2 * 0.027814921575518937f * c3 * P33;

  float* base = sum_sph + (size_t)i * 128;
#pragma unroll
  for (int k = 0; k < NSPH; ++k) {
    float sk = sph[k];
#pragma unroll
    for (int w = 0; w < NWAVE; ++w)
      unsafeAtomicAdd(base + k * 8 + w, sk * aw[w]);
  }
}

// ---------------- Kernel 3: Wigner-3j contraction ----------------
__global__ __launch_bounds__(256) void contract_kernel(
    const float* __restrict__ sum_sph, float* __restrict__ out, W3JT tbl)
{
  __shared__ float lds[256 * 17];  // stride 17: bank-conflict-free
  int t = blockIdx.x * 256 + threadIdx.x;
  if (t >= NATOM * NWAVE) return;
  int a = t >> 3, w = t & 7;
  float* s = lds + threadIdx.x * 17;
#pragma unroll
  for (int k = 0; k < NSPH; ++k) s[k] = sum_sph[(size_t)a * 128 + k * 8 + w];

#pragma unroll
  for (int j = 0; j < 6; ++j) {
    float acc = 0.f;
    int n = tbl.cnt[j];
    for (int q = 0; q < n; ++q)
      acc += s[tbl.k1[j][q]] * s[tbl.k2[j][q]] * s[tbl.k3[j][q]] * tbl.cf[j][q];
    out[((size_t)j * NATOM + a) * 8 + w] = acc;
  }
}

// ---------------- host: exact Wigner 3j (Racah) ----------------
static double dfact(int n) { double r = 1.0; for (int i = 2; i <= n; ++i) r *= i; return r; }
static double wig3j(int j1, int j2, int j3, int m1, int m2, int m3) {
  if (m1 + m2 + m3 != 0) return 0.0;
  double pre = sqrt(dfact(j1 + j2 - j3) * dfact(j1 - j2 + j3) * dfact(-j1 + j2 + j3)
                    / dfact(j1 + j2 + j3 + 1)
                    * dfact(j1 + m1) * dfact(j1 - m1) * dfact(j2 + m2) * dfact(j2 - m2)
                    * dfact(j3 + m3) * dfact(j3 - m3));
  int tmin = std::max(0, std::max(j2 - j3 - m1, j1 - j3 + m2));
  int tmax = std::min(j1 + j2 - j3, std::min(j1 - m1, j2 + m2));
  double s = 0.0;
  for (int t = tmin; t <= tmax; ++t)
    s += ((t & 1) ? -1.0 : 1.0) /
         (dfact(t) * dfact(j3 - j2 + m1 + t) * dfact(j3 - j1 - m2 + t) *
          dfact(j1 + j2 - j3 - t) * dfact(j1 - m1 - t) * dfact(j2 + m2 - t));
  int e = j1 - j2 - m3;
  double sgn = ((e % 2) != 0) ? -1.0 : 1.0;
  return sgn * pre * s;
}

extern "C" void kernel_launch(void* const* d_in, const int* in_sizes, int n_in,
                              void* d_out, int out_size, void* d_ws, size_t ws_size,
                              hipStream_t stream)
{
  const float* cart    = (const float*)d_in[0];
  const int*   aidx    = (const int*)d_in[1];
  const float* shifts  = (const float*)d_in[2];
  const float* species = (const float*)d_in[3];
  const float* W1 = (const float*)d_in[4];
  const float* b1 = (const float*)d_in[5];
  const float* W2 = (const float*)d_in[6];
  const float* b2 = (const float*)d_in[7];
  const float* W3 = (const float*)d_in[8];
  const float* b3 = (const float*)d_in[9];
  float* out = (float*)d_out;

  float* emb     = (float*)d_ws;                 // NATOM*24 floats
  float* sum_sph = emb + (size_t)NATOM * 24;     // NATOM*128 floats

  // Build Wigner-3j term table (deterministic, input-independent)
  static const int JS[6][3] = {{1,1,0},{1,1,2},{2,2,2},{2,2,0},{1,2,3},{3,3,2}};
  W3JT tbl;
  for (int j = 0; j < 6; ++j) {
    int J0 = JS[j][0], J1 = JS[j][1], J2 = JS[j][2];
    int n0 = J0 * (J0 + 1), n1 = J1 * (J1 + 1), n2 = J2 * (J2 + 1);
    int c = 0;
    for (int m1 = -J0; m1 <= J0; ++m1)
      for (int m2 = std::max(-J2 - m1, -J1); m2 <= std::min(J2 - m1, J1); ++m2) {
        int m3 = -m1 - m2;
        double w = wig3j(J0, J1, J2, m1, m2, m3);
        if (w == 0.0) continue;
        tbl.k1[j][c] = n0 + m1;
        tbl.k2[j][c] = n1 + m2;
        tbl.k3[j][c] = n2 + m3;
        tbl.cf[j][c] = (float)w;
        ++c;
      }
    tbl.cnt[j] = c;
  }

  hipMemsetAsync(sum_sph, 0, (size_t)NATOM * 128 * sizeof(float), stream);
  emb_kernel<<<(NATOM + 255) / 256, 256, 0, stream>>>(species, W1, b1, W2, b2, W3, b3, emb);
  neigh_kernel<<<(NEIGH + 255) / 256, 256, 0, stream>>>(cart, aidx, shifts, emb, sum_sph);
  contract_kernel<<<(NATOM * NWAVE + 255) / 256, 256, 0, stream>>>(sum_sph, out, tbl);
}

// Round 2
// 173.489 us; speedup vs baseline: 23.0483x; 23.0483x over previous
//
#include <hip/hip_runtime.h>
#include <math.h>
#include <algorithm>

#define NATOM 20000
#define NEIGH 600000
#define NWAVE 8
#define NSPH 16
// sum_sph layout: [atom][k(16)][w(8)] -> atom*128 + k*8 + w
// sorted layout:  [slot][24]: sph[0..15], aw[0..7]

struct W3JT {
  int cnt[6];
  int k1[6][32];
  int k2[6][32];
  int k3[6][32];
  float cf[6][32];
};

__device__ __forceinline__ float silu_f(float x) { return x / (1.f + expf(-x)); }

// ---------------- Kernel 1: per-atom embedding MLP ----------------
__global__ __launch_bounds__(256) void emb_kernel(
    const float* __restrict__ species,
    const float* __restrict__ W1, const float* __restrict__ b1,
    const float* __restrict__ W2, const float* __restrict__ b2,
    const float* __restrict__ W3, const float* __restrict__ b3,
    float* __restrict__ emb)
{
  int a = blockIdx.x * 256 + threadIdx.x;
  if (a >= NATOM) return;
  float spv = species[a];
  float h1[16], h2[16];
#pragma unroll
  for (int c = 0; c < 16; ++c) {
    float v = spv * W1[c] + b1[c];
    h1[c] = silu_f(v);
  }
#pragma unroll
  for (int d = 0; d < 16; ++d) {
    float v = b2[d];
#pragma unroll
    for (int c = 0; c < 16; ++c) v += h1[c] * W2[c * 16 + d];
    h2[d] = silu_f(v);
  }
#pragma unroll
  for (int e = 0; e < 24; ++e) {
    float v = b3[e];
#pragma unroll
    for (int c = 0; c < 16; ++c) v += h2[c] * W3[c * 24 + e];
    emb[a * 24 + e] = v;
  }
}

// ---------------- Kernel 2: histogram of center atoms ----------------
__global__ __launch_bounds__(256) void hist_kernel(
    const int* __restrict__ aidx, int* __restrict__ counts)
{
  int n = blockIdx.x * 256 + threadIdx.x;
  if (n >= NEIGH) return;
  atomicAdd(&counts[aidx[n]], 1);
}

// ---------------- Kernel 3: exclusive scan (single workgroup) ----------------
__global__ __launch_bounds__(1024) void scan_kernel(
    const int* __restrict__ counts, int* __restrict__ offsets)
{
  __shared__ int psum[1024];
  int tid = threadIdx.x;
  const int PER = (NATOM + 1023) / 1024;  // 20
  int base = tid * PER;
  int s = 0;
  for (int q = 0; q < PER; ++q) {
    int idx = base + q;
    if (idx < NATOM) s += counts[idx];
  }
  psum[tid] = s;
  __syncthreads();
  for (int off = 1; off < 1024; off <<= 1) {
    int v = (tid >= off) ? psum[tid - off] : 0;
    __syncthreads();
    psum[tid] += v;
    __syncthreads();
  }
  int run = (tid == 0) ? 0 : psum[tid - 1];
  for (int q = 0; q < PER; ++q) {
    int idx = base + q;
    if (idx < NATOM) { offsets[idx] = run; run += counts[idx]; }
  }
  if (tid == 1023) offsets[NATOM] = run;
}

// ---------------- Kernel 4: per-neighbor compute + sorted scatter ----------------
__global__ __launch_bounds__(256) void neigh_compute_kernel(
    const float* __restrict__ cart, const int* __restrict__ aidx,
    const float* __restrict__ shifts, const float* __restrict__ emb,
    const int* __restrict__ offsets, int* __restrict__ cursor,
    float* __restrict__ sorted)
{
  int n = blockIdx.x * 256 + threadIdx.x;
  if (n >= NEIGH) return;
  int i = aidx[n];
  int j = aidx[NEIGH + n];
  float cx = cart[j]             - cart[i]             + shifts[n];
  float cy = cart[NATOM + j]     - cart[NATOM + i]     + shifts[NEIGH + n];
  float cz = cart[2 * NATOM + j] - cart[2 * NATOM + i] + shifts[2 * NEIGH + n];
  float dist = sqrtf(cx * cx + cy * cy + cz * cz);
  float inv = 1.f / dist;
  float x = cx * inv, y = cy * inv, z = cz * inv;

  float cc = __cosf(dist * 0.62831853071795864769f);
  float cut0 = (cc + 1.f) * 0.5f;
  float cut = cut0 * cut0 * cut0;

  const float* e = emb + j * 24;
  float aw[NWAVE];
#pragma unroll
  for (int w = 0; w < NWAVE; ++w) {
    float coeff = e[w], alpha = e[8 + w], center = e[16 + w];
    float sd = alpha * (dist - center);
    aw[w] = cut * coeff * __expf(-sd * sd);
  }

  float sz = sqrtf(fmaxf(1.f - z * z, 0.f));
  float rxy = sqrtf(x * x + y * y);
  float cp, sp;
  if (rxy > 0.f) { float ri = 1.f / rxy; cp = x * ri; sp = y * ri; }
  else           { cp = 1.f; sp = 0.f; }
  float c2 = cp * cp - sp * sp, s2 = 2.f * cp * sp;
  float c3 = c2 * cp - s2 * sp, s3 = s2 * cp + c2 * sp;

  float P11 = -sz;
  float P22 = -3.f * sz * P11;
  float P33 = -5.f * sz * P22;
  float P10 = z;
  float P21 = 3.f * z * P11;
  float P32 = 5.f * z * P22;
  float P20 = (3.f * z * P10 - 1.f) * 0.5f;
  float P31 = (5.f * z * P21 - 3.f * P11) * 0.5f;
  float P30 = (5.f * z * P20 - 2.f * P10) * (1.f / 3.f);

  const float SQ2 = 1.41421356237309515f;
  float sph[NSPH];
  sph[0]  = 0.28209479177387814f;
  sph[1]  = SQ2 * 0.3454941494713355f  * sp * P11;
  sph[2]  = 0.4886025119029199f * P10;
  sph[3]  = SQ2 * 0.3454941494713355f  * cp * P11;
  sph[4]  = SQ2 * 0.12875806734106326f * s2 * P22;
  sph[5]  = SQ2 * 0.25751613468212653f * sp * P21;
  sph[6]  = 0.6307831305050401f * P20;
  sph[7]  = SQ2 * 0.25751613468212653f * cp * P21;
  sph[8]  = SQ2 * 0.12875806734106326f * c2 * P22;
  sph[9]  = SQ2 * 0.027814921575518937f * s3 * P33;
  sph[10] = SQ2 * 0.06813236509555433f  * s2 * P32;
  sph[11] = SQ2 * 0.2154534560761003f   * sp * P31;
  sph[12] = 0.7463526651802308f * P30;
  sph[13] = SQ2 * 0.2154534560761003f   * cp * P31;
  sph[14] = SQ2 * 0.06813236509555433f  * c2 * P32;
  sph[15] = SQ2 * 0.027814921575518937f * c3 * P33;

  int slot = offsets[i] + atomicAdd(&cursor[i], 1);
  float4* dst = reinterpret_cast<float4*>(sorted + (size_t)slot * 24);
  dst[0] = make_float4(sph[0],  sph[1],  sph[2],  sph[3]);
  dst[1] = make_float4(sph[4],  sph[5],  sph[6],  sph[7]);
  dst[2] = make_float4(sph[8],  sph[9],  sph[10], sph[11]);
  dst[3] = make_float4(sph[12], sph[13], sph[14], sph[15]);
  dst[4] = make_float4(aw[0], aw[1], aw[2], aw[3]);
  dst[5] = make_float4(aw[4], aw[5], aw[6], aw[7]);
}

// ---------------- Kernel 5: per-atom gather (atomic-free) ----------------
__global__ __launch_bounds__(256) void gather_kernel(
    const float* __restrict__ sorted, const int* __restrict__ offsets,
    float* __restrict__ sum_sph)
{
  int a = blockIdx.x * 256 + threadIdx.x;
  if (a >= NATOM) return;
  float acc[NSPH][NWAVE];
#pragma unroll
  for (int k = 0; k < NSPH; ++k)
#pragma unroll
    for (int w = 0; w < NWAVE; ++w) acc[k][w] = 0.f;

  int s0 = offsets[a], s1 = offsets[a + 1];
  for (int s = s0; s < s1; ++s) {
    const float4* p = reinterpret_cast<const float4*>(sorted + (size_t)s * 24);
    float4 v0 = p[0], v1 = p[1], v2 = p[2], v3 = p[3], v4 = p[4], v5 = p[5];
    float sph[NSPH] = {v0.x, v0.y, v0.z, v0.w, v1.x, v1.y, v1.z, v1.w,
                       v2.x, v2.y, v2.z, v2.w, v3.x, v3.y, v3.z, v3.w};
    float aw[NWAVE] = {v4.x, v4.y, v4.z, v4.w, v5.x, v5.y, v5.z, v5.w};
#pragma unroll
    for (int k = 0; k < NSPH; ++k)
#pragma unroll
      for (int w = 0; w < NWAVE; ++w) acc[k][w] += sph[k] * aw[w];
  }

  float4* dst = reinterpret_cast<float4*>(sum_sph + (size_t)a * 128);
#pragma unroll
  for (int k = 0; k < NSPH; ++k) {
    dst[k * 2]     = make_float4(acc[k][0], acc[k][1], acc[k][2], acc[k][3]);
    dst[k * 2 + 1] = make_float4(acc[k][4], acc[k][5], acc[k][6], acc[k][7]);
  }
}

// ---------------- Kernel 6: Wigner-3j contraction ----------------
__global__ __launch_bounds__(256) void contract_kernel(
    const float* __restrict__ sum_sph, float* __restrict__ out, W3JT tbl)
{
  __shared__ float lds[256 * 17];  // stride 17: bank-conflict-free
  int t = blockIdx.x * 256 + threadIdx.x;
  if (t >= NATOM * NWAVE) return;
  int a = t >> 3, w = t & 7;
  float* s = lds + threadIdx.x * 17;
#pragma unroll
  for (int k = 0; k < NSPH; ++k) s[k] = sum_sph[(size_t)a * 128 + k * 8 + w];

#pragma unroll
  for (int j = 0; j < 6; ++j) {
    float acc = 0.f;
    int n = tbl.cnt[j];
    for (int q = 0; q < n; ++q)
      acc += s[tbl.k1[j][q]] * s[tbl.k2[j][q]] * s[tbl.k3[j][q]] * tbl.cf[j][q];
    out[((size_t)j * NATOM + a) * 8 + w] = acc;
  }
}

// ---------------- host: exact Wigner 3j (Racah) ----------------
static double dfact(int n) { double r = 1.0; for (int i = 2; i <= n; ++i) r *= i; return r; }
static double wig3j(int j1, int j2, int j3, int m1, int m2, int m3) {
  if (m1 + m2 + m3 != 0) return 0.0;
  double pre = sqrt(dfact(j1 + j2 - j3) * dfact(j1 - j2 + j3) * dfact(-j1 + j2 + j3)
                    / dfact(j1 + j2 + j3 + 1)
                    * dfact(j1 + m1) * dfact(j1 - m1) * dfact(j2 + m2) * dfact(j2 - m2)
                    * dfact(j3 + m3) * dfact(j3 - m3));
  int tmin = std::max(0, std::max(j2 - j3 - m1, j1 - j3 + m2));
  int tmax = std::min(j1 + j2 - j3, std::min(j1 - m1, j2 + m2));
  double s = 0.0;
  for (int t = tmin; t <= tmax; ++t)
    s += ((t & 1) ? -1.0 : 1.0) /
         (dfact(t) * dfact(j3 - j2 + m1 + t) * dfact(j3 - j1 - m2 + t) *
          dfact(j1 + j2 - j3 - t) * dfact(j1 - m1 - t) * dfact(j2 + m2 - t));
  int e = j1 - j2 - m3;
  double sgn = ((e % 2) != 0) ? -1.0 : 1.0;
  return sgn * pre * s;
}

extern "C" void kernel_launch(void* const* d_in, const int* in_sizes, int n_in,
                              void* d_out, int out_size, void* d_ws, size_t ws_size,
                              hipStream_t stream)
{
  const float* cart    = (const float*)d_in[0];
  const int*   aidx    = (const int*)d_in[1];
  const float* shifts  = (const float*)d_in[2];
  const float* species = (const float*)d_in[3];
  const float* W1 = (const float*)d_in[4];
  const float* b1 = (const float*)d_in[5];
  const float* W2 = (const float*)d_in[6];
  const float* b2 = (const float*)d_in[7];
  const float* W3 = (const float*)d_in[8];
  const float* b3 = (const float*)d_in[9];
  float* out = (float*)d_out;

  // ws layout (floats), sorted first for 16B alignment of float4 access
  float* sorted  = (float*)d_ws;                         // 600000*24
  float* emb     = sorted + (size_t)NEIGH * 24;          // 20000*24
  float* sum_sph = emb + (size_t)NATOM * 24;             // 20000*128
  int*   counts  = (int*)(sum_sph + (size_t)NATOM * 128); // 20000
  int*   cursor  = counts + NATOM;                        // 20000
  int*   offsets = cursor + NATOM;                        // 20001

  // Build Wigner-3j term table (deterministic, input-independent)
  static const int JS[6][3] = {{1,1,0},{1,1,2},{2,2,2},{2,2,0},{1,2,3},{3,3,2}};
  W3JT tbl;
  for (int j = 0; j < 6; ++j) {
    int J0 = JS[j][0], J1 = JS[j][1], J2 = JS[j][2];
    int n0 = J0 * (J0 + 1), n1 = J1 * (J1 + 1), n2 = J2 * (J2 + 1);
    int c = 0;
    for (int m1 = -J0; m1 <= J0; ++m1)
      for (int m2 = std::max(-J2 - m1, -J1); m2 <= std::min(J2 - m1, J1); ++m2) {
        int m3 = -m1 - m2;
        double w = wig3j(J0, J1, J2, m1, m2, m3);
        if (w == 0.0) continue;
        tbl.k1[j][c] = n0 + m1;
        tbl.k2[j][c] = n1 + m2;
        tbl.k3[j][c] = n2 + m3;
        tbl.cf[j][c] = (float)w;
        ++c;
      }
    tbl.cnt[j] = c;
  }

  hipMemsetAsync(counts, 0, (size_t)2 * NATOM * sizeof(int), stream);  // counts+cursor
  emb_kernel<<<(NATOM + 255) / 256, 256, 0, stream>>>(species, W1, b1, W2, b2, W3, b3, emb);
  hist_kernel<<<(NEIGH + 255) / 256, 256, 0, stream>>>(aidx, counts);
  scan_kernel<<<1, 1024, 0, stream>>>(counts, offsets);
  neigh_compute_kernel<<<(NEIGH + 255) / 256, 256, 0, stream>>>(
      cart, aidx, shifts, emb, offsets, cursor, sorted);
  gather_kernel<<<(NATOM + 255) / 256, 256, 0, stream>>>(sorted, offsets, sum_sph);
  contract_kernel<<<(NATOM * NWAVE + 255) / 256, 256, 0, stream>>>(sum_sph, out, tbl);
}

// Round 3
// 169.797 us; speedup vs baseline: 23.5494x; 1.0217x over previous
//
#include <hip/hip_runtime.h>
#include <math.h>
#include <algorithm>
#include <string.h>

#define NATOM 20000
#define NEIGH 600000
#define NWAVE 8
#define NSPH 16
// sortrec layout: [slot] = float4 { asfloat(j), sx, sy, sz }

struct CFT {
  float v[6][7][7];  // [jseq][m1+3][m2+3], zero where invalid
};

__device__ __forceinline__ float silu_f(float x) { return x / (1.f + expf(-x)); }

// ---------------- Kernel 1: per-atom embedding MLP ----------------
__global__ __launch_bounds__(256) void emb_kernel(
    const float* __restrict__ species,
    const float* __restrict__ W1, const float* __restrict__ b1,
    const float* __restrict__ W2, const float* __restrict__ b2,
    const float* __restrict__ W3, const float* __restrict__ b3,
    float* __restrict__ emb)
{
  int a = blockIdx.x * 256 + threadIdx.x;
  if (a >= NATOM) return;
  float spv = species[a];
  float h1[16], h2[16];
#pragma unroll
  for (int c = 0; c < 16; ++c) {
    float v = spv * W1[c] + b1[c];
    h1[c] = silu_f(v);
  }
#pragma unroll
  for (int d = 0; d < 16; ++d) {
    float v = b2[d];
#pragma unroll
    for (int c = 0; c < 16; ++c) v += h1[c] * W2[c * 16 + d];
    h2[d] = silu_f(v);
  }
#pragma unroll
  for (int e = 0; e < 24; ++e) {
    float v = b3[e];
#pragma unroll
    for (int c = 0; c < 16; ++c) v += h2[c] * W3[c * 24 + e];
    emb[a * 24 + e] = v;
  }
}

// ---------------- Kernel 2: histogram of center atoms ----------------
__global__ __launch_bounds__(256) void hist_kernel(
    const int* __restrict__ aidx, int* __restrict__ counts)
{
  int n = blockIdx.x * 256 + threadIdx.x;
  if (n >= NEIGH) return;
  atomicAdd(&counts[aidx[n]], 1);
}

// ---------------- Kernel 3: exclusive scan (single workgroup) ----------------
__global__ __launch_bounds__(1024) void scan_kernel(
    const int* __restrict__ counts, int* __restrict__ offsets)
{
  __shared__ int psum[1024];
  int tid = threadIdx.x;
  const int PER = (NATOM + 1023) / 1024;  // 20
  int base = tid * PER;
  int s = 0;
  for (int q = 0; q < PER; ++q) {
    int idx = base + q;
    if (idx < NATOM) s += counts[idx];
  }
  psum[tid] = s;
  __syncthreads();
  for (int off = 1; off < 1024; off <<= 1) {
    int v = (tid >= off) ? psum[tid - off] : 0;
    __syncthreads();
    psum[tid] += v;
    __syncthreads();
  }
  int run = (tid == 0) ? 0 : psum[tid - 1];
  for (int q = 0; q < PER; ++q) {
    int idx = base + q;
    if (idx < NATOM) { offsets[idx] = run; run += counts[idx]; }
  }
  if (tid == 1023) offsets[NATOM] = run;
}

// ---------------- Kernel 4: sort neighbor identities (16B records) ----------------
__global__ __launch_bounds__(256) void rank_kernel(
    const int* __restrict__ aidx, const float* __restrict__ shifts,
    const int* __restrict__ offsets, int* __restrict__ cursor,
    float4* __restrict__ sortrec)
{
  int n = blockIdx.x * 256 + threadIdx.x;
  if (n >= NEIGH) return;
  int i = aidx[n];
  int j = aidx[NEIGH + n];
  int slot = offsets[i] + atomicAdd(&cursor[i], 1);
  float4 r;
  r.x = __int_as_float(j);
  r.y = shifts[n];
  r.z = shifts[NEIGH + n];
  r.w = shifts[2 * NEIGH + n];
  sortrec[slot] = r;
}

// ---------------- Kernel 5: fused compute + accumulate + Wigner contraction ----------------
// thread = (atom, w); each thread owns one wave channel, acc[16] in registers.
__global__ __launch_bounds__(256) void fused_kernel(
    const float* __restrict__ cart, const float4* __restrict__ sortrec,
    const float* __restrict__ emb, const int* __restrict__ offsets,
    float* __restrict__ out, CFT cf)
{
  int t = blockIdx.x * 256 + threadIdx.x;
  int a = t >> 3;
  int w = t & 7;
  if (a >= NATOM) return;

  float xi = cart[a], yi = cart[NATOM + a], zi = cart[2 * NATOM + a];
  int s0 = offsets[a], s1 = offsets[a + 1];

  float acc[NSPH];
#pragma unroll
  for (int k = 0; k < NSPH; ++k) acc[k] = 0.f;

  const float SQ2 = 1.41421356237309515f;
  for (int s = s0; s < s1; ++s) {
    float4 r = sortrec[s];
    int j = __float_as_int(r.x);
    float cx = cart[j]             - xi + r.y;
    float cy = cart[NATOM + j]     - yi + r.z;
    float cz = cart[2 * NATOM + j] - zi + r.w;
    float d2 = cx * cx + cy * cy + cz * cz;
    float dist = sqrtf(d2);
    float inv = 1.f / dist;
    float x = cx * inv, y = cy * inv, z = cz * inv;

    float cc = __cosf(dist * 0.62831853071795864769f);
    float cut0 = (cc + 1.f) * 0.5f;
    float cut = cut0 * cut0 * cut0;

    const float* e = emb + j * 24;
    float coeff = e[w], alpha = e[8 + w], center = e[16 + w];
    float sd = alpha * (dist - center);
    float av = cut * coeff * __expf(-sd * sd);

    float sz = sqrtf(fmaxf(1.f - z * z, 0.f));
    float rxy = sqrtf(x * x + y * y);
    float cp, sp;
    if (rxy > 0.f) { float ri = 1.f / rxy; cp = x * ri; sp = y * ri; }
    else           { cp = 1.f; sp = 0.f; }
    float c2 = cp * cp - sp * sp, s2 = 2.f * cp * sp;
    float c3 = c2 * cp - s2 * sp, s3 = s2 * cp + c2 * sp;

    float P11 = -sz;
    float P22 = -3.f * sz * P11;
    float P33 = -5.f * sz * P22;
    float P10 = z;
    float P21 = 3.f * z * P11;
    float P32 = 5.f * z * P22;
    float P20 = (3.f * z * P10 - 1.f) * 0.5f;
    float P31 = (5.f * z * P21 - 3.f * P11) * 0.5f;
    float P30 = (5.f * z * P20 - 2.f * P10) * (1.f / 3.f);

    float sph[NSPH];
    sph[0]  = 0.28209479177387814f;
    sph[1]  = SQ2 * 0.3454941494713355f  * sp * P11;
    sph[2]  = 0.4886025119029199f * P10;
    sph[3]  = SQ2 * 0.3454941494713355f  * cp * P11;
    sph[4]  = SQ2 * 0.12875806734106326f * s2 * P22;
    sph[5]  = SQ2 * 0.25751613468212653f * sp * P21;
    sph[6]  = 0.6307831305050401f * P20;
    sph[7]  = SQ2 * 0.25751613468212653f * cp * P21;
    sph[8]  = SQ2 * 0.12875806734106326f * c2 * P22;
    sph[9]  = SQ2 * 0.027814921575518937f * s3 * P33;
    sph[10] = SQ2 * 0.06813236509555433f  * s2 * P32;
    sph[11] = SQ2 * 0.2154534560761003f   * sp * P31;
    sph[12] = 0.7463526651802308f * P30;
    sph[13] = SQ2 * 0.2154534560761003f   * cp * P31;
    sph[14] = SQ2 * 0.06813236509555433f  * c2 * P32;
    sph[15] = SQ2 * 0.027814921575518937f * c3 * P33;

#pragma unroll
    for (int k = 0; k < NSPH; ++k) acc[k] += sph[k] * av;
  }

  // Wigner contraction, fully unrolled static indices
  constexpr int J0s[6] = {1, 1, 2, 2, 1, 3};
  constexpr int J1s[6] = {1, 1, 2, 2, 2, 3};
  constexpr int J2s[6] = {0, 2, 2, 0, 3, 2};
#pragma unroll
  for (int jj = 0; jj < 6; ++jj) {
    const int J0 = J0s[jj], J1 = J1s[jj], J2 = J2s[jj];
    const int n0 = J0 * (J0 + 1), n1 = J1 * (J1 + 1), n2 = J2 * (J2 + 1);
    float dj = 0.f;
#pragma unroll
    for (int m1 = -3; m1 <= 3; ++m1) {
      if (m1 < -J0 || m1 > J0) continue;
#pragma unroll
      for (int m2 = -3; m2 <= 3; ++m2) {
        if (m2 < -J1 || m2 > J1) continue;
        const int m3 = -m1 - m2;
        if (m3 < -J2 || m3 > J2) continue;
        dj += acc[n0 + m1] * acc[n1 + m2] * acc[n2 + m3] * cf.v[jj][m1 + 3][m2 + 3];
      }
    }
    out[((size_t)jj * NATOM + a) * 8 + w] = dj;
  }
}

// ---------------- host: exact Wigner 3j (Racah) ----------------
static double dfact(int n) { double r = 1.0; for (int i = 2; i <= n; ++i) r *= i; return r; }
static double wig3j(int j1, int j2, int j3, int m1, int m2, int m3) {
  if (m1 + m2 + m3 != 0) return 0.0;
  double pre = sqrt(dfact(j1 + j2 - j3) * dfact(j1 - j2 + j3) * dfact(-j1 + j2 + j3)
                    / dfact(j1 + j2 + j3 + 1)
                    * dfact(j1 + m1) * dfact(j1 - m1) * dfact(j2 + m2) * dfact(j2 - m2)
                    * dfact(j3 + m3) * dfact(j3 - m3));
  int tmin = std::max(0, std::max(j2 - j3 - m1, j1 - j3 + m2));
  int tmax = std::min(j1 + j2 - j3, std::min(j1 - m1, j2 + m2));
  double s = 0.0;
  for (int t = tmin; t <= tmax; ++t)
    s += ((t & 1) ? -1.0 : 1.0) /
         (dfact(t) * dfact(j3 - j2 + m1 + t) * dfact(j3 - j1 - m2 + t) *
          dfact(j1 + j2 - j3 - t) * dfact(j1 - m1 - t) * dfact(j2 + m2 - t));
  int e = j1 - j2 - m3;
  double sgn = ((e % 2) != 0) ? -1.0 : 1.0;
  return sgn * pre * s;
}

extern "C" void kernel_launch(void* const* d_in, const int* in_sizes, int n_in,
                              void* d_out, int out_size, void* d_ws, size_t ws_size,
                              hipStream_t stream)
{
  const float* cart    = (const float*)d_in[0];
  const int*   aidx    = (const int*)d_in[1];
  const float* shifts  = (const float*)d_in[2];
  const float* species = (const float*)d_in[3];
  const float* W1 = (const float*)d_in[4];
  const float* b1 = (const float*)d_in[5];
  const float* W2 = (const float*)d_in[6];
  const float* b2 = (const float*)d_in[7];
  const float* W3 = (const float*)d_in[8];
  const float* b3 = (const float*)d_in[9];
  float* out = (float*)d_out;

  // ws layout: sortrec (16B-aligned) | emb | counts | cursor | offsets
  float4* sortrec = (float4*)d_ws;                        // NEIGH float4
  float*  emb     = (float*)(sortrec + NEIGH);            // NATOM*24
  int*    counts  = (int*)(emb + (size_t)NATOM * 24);     // NATOM
  int*    cursor  = counts + NATOM;                       // NATOM
  int*    offsets = cursor + NATOM;                       // NATOM+1

  // Dense Wigner-3j coefficient cube (deterministic, input-independent)
  static const int JS[6][3] = {{1,1,0},{1,1,2},{2,2,2},{2,2,0},{1,2,3},{3,3,2}};
  CFT cf;
  memset(&cf, 0, sizeof(cf));
  for (int j = 0; j < 6; ++j) {
    int J0 = JS[j][0], J1 = JS[j][1], J2 = JS[j][2];
    for (int m1 = -J0; m1 <= J0; ++m1)
      for (int m2 = std::max(-J2 - m1, -J1); m2 <= std::min(J2 - m1, J1); ++m2) {
        int m3 = -m1 - m2;
        cf.v[j][m1 + 3][m2 + 3] = (float)wig3j(J0, J1, J2, m1, m2, m3);
      }
  }

  hipMemsetAsync(counts, 0, (size_t)2 * NATOM * sizeof(int), stream);  // counts+cursor
  emb_kernel<<<(NATOM + 255) / 256, 256, 0, stream>>>(species, W1, b1, W2, b2, W3, b3, emb);
  hist_kernel<<<(NEIGH + 255) / 256, 256, 0, stream>>>(aidx, counts);
  scan_kernel<<<1, 1024, 0, stream>>>(counts, offsets);
  rank_kernel<<<(NEIGH + 255) / 256, 256, 0, stream>>>(aidx, shifts, offsets, cursor, sortrec);
  fused_kernel<<<(NATOM * NWAVE + 255) / 256, 256, 0, stream>>>(
      cart, sortrec, emb, offsets, out, cf);
}

// Round 4
// 130.062 us; speedup vs baseline: 30.7440x; 1.3055x over previous
//
#include <hip/hip_runtime.h>
#include <math.h>
#include <algorithm>
#include <string.h>

#define NATOM 20000
#define NEIGH 600000
#define NWAVE 8
#define NSPH 16
// sortrec layout: [slot] = float4 { asfloat(j), sx, sy, sz }

struct CFT {
  float v[6][7][7];  // [jseq][m1+3][m2+3], zero where invalid
};

__device__ __forceinline__ float silu_f(float x) { return x / (1.f + expf(-x)); }

// ---------------- Kernel 1: embedding MLP (first NATOM threads) + center-atom histogram ----------------
__global__ __launch_bounds__(256) void emb_hist_kernel(
    const float* __restrict__ species,
    const float* __restrict__ W1, const float* __restrict__ b1,
    const float* __restrict__ W2, const float* __restrict__ b2,
    const float* __restrict__ W3, const float* __restrict__ b3,
    float* __restrict__ emb,
    const int* __restrict__ aidx, int* __restrict__ counts,
    int* __restrict__ rank_n)
{
  int t = blockIdx.x * 256 + threadIdx.x;
  if (t < NATOM) {
    float spv = species[t];
    float h1[16], h2[16];
#pragma unroll
    for (int c = 0; c < 16; ++c) {
      float v = spv * W1[c] + b1[c];
      h1[c] = silu_f(v);
    }
#pragma unroll
    for (int d = 0; d < 16; ++d) {
      float v = b2[d];
#pragma unroll
      for (int c = 0; c < 16; ++c) v += h1[c] * W2[c * 16 + d];
      h2[d] = silu_f(v);
    }
#pragma unroll
    for (int e = 0; e < 24; ++e) {
      float v = b3[e];
#pragma unroll
      for (int c = 0; c < 16; ++c) v += h2[c] * W3[c * 24 + e];
      emb[t * 24 + e] = v;
    }
  }
  if (t < NEIGH) {
    int i = aidx[t];
    rank_n[t] = atomicAdd(&counts[i], 1);
  }
}

// ---------------- Kernel 2: exclusive scan (single workgroup) ----------------
__global__ __launch_bounds__(1024) void scan_kernel(
    const int* __restrict__ counts, int* __restrict__ offsets)
{
  __shared__ int psum[1024];
  int tid = threadIdx.x;
  const int PER = (NATOM + 1023) / 1024;  // 20
  int base = tid * PER;
  int s = 0;
  for (int q = 0; q < PER; ++q) {
    int idx = base + q;
    if (idx < NATOM) s += counts[idx];
  }
  psum[tid] = s;
  __syncthreads();
  for (int off = 1; off < 1024; off <<= 1) {
    int v = (tid >= off) ? psum[tid - off] : 0;
    __syncthreads();
    psum[tid] += v;
    __syncthreads();
  }
  int run = (tid == 0) ? 0 : psum[tid - 1];
  for (int q = 0; q < PER; ++q) {
    int idx = base + q;
    if (idx < NATOM) { offsets[idx] = run; run += counts[idx]; }
  }
  if (tid == 1023) offsets[NATOM] = run;
}

// ---------------- Kernel 3: sorted scatter of neighbor identities (no atomics) ----------------
__global__ __launch_bounds__(256) void rank_kernel(
    const int* __restrict__ aidx, const float* __restrict__ shifts,
    const int* __restrict__ offsets, const int* __restrict__ rank_n,
    float4* __restrict__ sortrec)
{
  int n = blockIdx.x * 256 + threadIdx.x;
  if (n >= NEIGH) return;
  int i = aidx[n];
  int slot = offsets[i] + rank_n[n];
  float4 r;
  r.x = __int_as_float(aidx[NEIGH + n]);
  r.y = shifts[n];
  r.z = shifts[NEIGH + n];
  r.w = shifts[2 * NEIGH + n];
  sortrec[slot] = r;
}

// ---------------- Kernel 4: fused compute + accumulate + Wigner contraction ----------------
// 16 threads per atom: sub = (half<<3) | w. Each (w,half) walks half the
// neighbor run with acc[16] in registers; halves combine via shfl_xor(8).
__global__ __launch_bounds__(256) void fused_kernel(
    const float* __restrict__ cart, const float4* __restrict__ sortrec,
    const float* __restrict__ emb, const int* __restrict__ offsets,
    float* __restrict__ out, CFT cf)
{
  int t = blockIdx.x * 256 + threadIdx.x;
  int a = t >> 4;
  int sub = t & 15;
  int w = sub & 7;
  int half = sub >> 3;
  if (a >= NATOM) return;

  float xi = cart[a], yi = cart[NATOM + a], zi = cart[2 * NATOM + a];
  int s0 = offsets[a], s1 = offsets[a + 1];

  float acc[NSPH];
#pragma unroll
  for (int k = 0; k < NSPH; ++k) acc[k] = 0.f;

  const float SQ2 = 1.41421356237309515f;
  for (int s = s0 + half; s < s1; s += 2) {
    float4 r = sortrec[s];
    int j = __float_as_int(r.x);
    float cx = cart[j]             - xi + r.y;
    float cy = cart[NATOM + j]     - yi + r.z;
    float cz = cart[2 * NATOM + j] - zi + r.w;
    float d2 = cx * cx + cy * cy + cz * cz;
    float dist = sqrtf(d2);
    float inv = 1.f / dist;
    float x = cx * inv, y = cy * inv, z = cz * inv;

    float cc = __cosf(dist * 0.62831853071795864769f);
    float cut0 = (cc + 1.f) * 0.5f;
    float cut = cut0 * cut0 * cut0;

    const float* e = emb + j * 24;
    float coeff = e[w], alpha = e[8 + w], center = e[16 + w];
    float sd = alpha * (dist - center);
    float av = cut * coeff * __expf(-sd * sd);

    float sz = sqrtf(fmaxf(1.f - z * z, 0.f));
    float rxy = sqrtf(x * x + y * y);
    float cp, sp;
    if (rxy > 0.f) { float ri = 1.f / rxy; cp = x * ri; sp = y * ri; }
    else           { cp = 1.f; sp = 0.f; }
    float c2 = cp * cp - sp * sp, s2 = 2.f * cp * sp;
    float c3 = c2 * cp - s2 * sp, s3 = s2 * cp + c2 * sp;

    float P11 = -sz;
    float P22 = -3.f * sz * P11;
    float P33 = -5.f * sz * P22;
    float P10 = z;
    float P21 = 3.f * z * P11;
    float P32 = 5.f * z * P22;
    float P20 = (3.f * z * P10 - 1.f) * 0.5f;
    float P31 = (5.f * z * P21 - 3.f * P11) * 0.5f;
    float P30 = (5.f * z * P20 - 2.f * P10) * (1.f / 3.f);

    float sph1  = SQ2 * 0.3454941494713355f  * sp * P11;
    float sph2  = 0.4886025119029199f * P10;
    float sph3  = SQ2 * 0.3454941494713355f  * cp * P11;
    float sph4  = SQ2 * 0.12875806734106326f * s2 * P22;
    float sph5  = SQ2 * 0.25751613468212653f * sp * P21;
    float sph6  = 0.6307831305050401f * P20;
    float sph7  = SQ2 * 0.25751613468212653f * cp * P21;
    float sph8  = SQ2 * 0.12875806734106326f * c2 * P22;
    float sph9  = SQ2 * 0.027814921575518937f * s3 * P33;
    float sph10 = SQ2 * 0.06813236509555433f  * s2 * P32;
    float sph11 = SQ2 * 0.2154534560761003f   * sp * P31;
    float sph12 = 0.7463526651802308f * P30;
    float sph13 = SQ2 * 0.2154534560761003f   * cp * P31;
    float sph14 = SQ2 * 0.06813236509555433f  * c2 * P32;
    float sph15 = SQ2 * 0.027814921575518937f * c3 * P33;

    acc[0]  += 0.28209479177387814f * av;
    acc[1]  += sph1  * av;
    acc[2]  += sph2  * av;
    acc[3]  += sph3  * av;
    acc[4]  += sph4  * av;
    acc[5]  += sph5  * av;
    acc[6]  += sph6  * av;
    acc[7]  += sph7  * av;
    acc[8]  += sph8  * av;
    acc[9]  += sph9  * av;
    acc[10] += sph10 * av;
    acc[11] += sph11 * av;
    acc[12] += sph12 * av;
    acc[13] += sph13 * av;
    acc[14] += sph14 * av;
    acc[15] += sph15 * av;
  }

  // combine the two halves (lanes differ in bit 3)
#pragma unroll
  for (int k = 0; k < NSPH; ++k) acc[k] += __shfl_xor(acc[k], 8);

  // Wigner contraction, fully unrolled static indices; half 0 writes jj 0-2,
  // half 1 writes jj 3-5 (both compute all six; it's ~160 cheap FMAs).
  constexpr int J0s[6] = {1, 1, 2, 2, 1, 3};
  constexpr int J1s[6] = {1, 1, 2, 2, 2, 3};
  constexpr int J2s[6] = {0, 2, 2, 0, 3, 2};
#pragma unroll
  for (int jj = 0; jj < 6; ++jj) {
    const int J0 = J0s[jj], J1 = J1s[jj], J2 = J2s[jj];
    const int n0 = J0 * (J0 + 1), n1 = J1 * (J1 + 1), n2 = J2 * (J2 + 1);
    float dj = 0.f;
#pragma unroll
    for (int m1 = -3; m1 <= 3; ++m1) {
      if (m1 < -J0 || m1 > J0) continue;
#pragma unroll
      for (int m2 = -3; m2 <= 3; ++m2) {
        if (m2 < -J1 || m2 > J1) continue;
        const int m3 = -m1 - m2;
        if (m3 < -J2 || m3 > J2) continue;
        dj += acc[n0 + m1] * acc[n1 + m2] * acc[n2 + m3] * cf.v[jj][m1 + 3][m2 + 3];
      }
    }
    if (half == (jj >= 3 ? 1 : 0))
      out[((size_t)jj * NATOM + a) * 8 + w] = dj;
  }
}

// ---------------- host: exact Wigner 3j (Racah) ----------------
static double dfact(int n) { double r = 1.0; for (int i = 2; i <= n; ++i) r *= i; return r; }
static double wig3j(int j1, int j2, int j3, int m1, int m2, int m3) {
  if (m1 + m2 + m3 != 0) return 0.0;
  double pre = sqrt(dfact(j1 + j2 - j3) * dfact(j1 - j2 + j3) * dfact(-j1 + j2 + j3)
                    / dfact(j1 + j2 + j3 + 1)
                    * dfact(j1 + m1) * dfact(j1 - m1) * dfact(j2 + m2) * dfact(j2 - m2)
                    * dfact(j3 + m3) * dfact(j3 - m3));
  int tmin = std::max(0, std::max(j2 - j3 - m1, j1 - j3 + m2));
  int tmax = std::min(j1 + j2 - j3, std::min(j1 - m1, j2 + m2));
  double s = 0.0;
  for (int t = tmin; t <= tmax; ++t)
    s += ((t & 1) ? -1.0 : 1.0) /
         (dfact(t) * dfact(j3 - j2 + m1 + t) * dfact(j3 - j1 - m2 + t) *
          dfact(j1 + j2 - j3 - t) * dfact(j1 - m1 - t) * dfact(j2 + m2 - t));
  int e = j1 - j2 - m3;
  double sgn = ((e % 2) != 0) ? -1.0 : 1.0;
  return sgn * pre * s;
}

extern "C" void kernel_launch(void* const* d_in, const int* in_sizes, int n_in,
                              void* d_out, int out_size, void* d_ws, size_t ws_size,
                              hipStream_t stream)
{
  const float* cart    = (const float*)d_in[0];
  const int*   aidx    = (const int*)d_in[1];
  const float* shifts  = (const float*)d_in[2];
  const float* species = (const float*)d_in[3];
  const float* W1 = (const float*)d_in[4];
  const float* b1 = (const float*)d_in[5];
  const float* W2 = (const float*)d_in[6];
  const float* b2 = (const float*)d_in[7];
  const float* W3 = (const float*)d_in[8];
  const float* b3 = (const float*)d_in[9];
  float* out = (float*)d_out;

  // ws layout: sortrec (16B-aligned) | emb | counts | rank_n | offsets
  float4* sortrec = (float4*)d_ws;                        // NEIGH float4
  float*  emb     = (float*)(sortrec + NEIGH);            // NATOM*24
  int*    counts  = (int*)(emb + (size_t)NATOM * 24);     // NATOM
  int*    rank_n  = counts + NATOM;                       // NEIGH
  int*    offsets = rank_n + NEIGH;                       // NATOM+1

  // Dense Wigner-3j coefficient cube (deterministic, input-independent)
  static const int JS[6][3] = {{1,1,0},{1,1,2},{2,2,2},{2,2,0},{1,2,3},{3,3,2}};
  CFT cf;
  memset(&cf, 0, sizeof(cf));
  for (int j = 0; j < 6; ++j) {
    int J0 = JS[j][0], J1 = JS[j][1], J2 = JS[j][2];
    for (int m1 = -J0; m1 <= J0; ++m1)
      for (int m2 = std::max(-J2 - m1, -J1); m2 <= std::min(J2 - m1, J1); ++m2) {
        int m3 = -m1 - m2;
        cf.v[j][m1 + 3][m2 + 3] = (float)wig3j(J0, J1, J2, m1, m2, m3);
      }
  }

  hipMemsetAsync(counts, 0, (size_t)NATOM * sizeof(int), stream);
  emb_hist_kernel<<<(NEIGH + 255) / 256, 256, 0, stream>>>(
      species, W1, b1, W2, b2, W3, b3, emb, aidx, counts, rank_n);
  scan_kernel<<<1, 1024, 0, stream>>>(counts, offsets);
  rank_kernel<<<(NEIGH + 255) / 256, 256, 0, stream>>>(aidx, shifts, offsets, rank_n, sortrec);
  fused_kernel<<<(NATOM * 16) / 256, 256, 0, stream>>>(
      cart, sortrec, emb, offsets, out, cf);
}

// Round 5
// 104.693 us; speedup vs baseline: 38.1936x; 1.2423x over previous
//
#include <hip/hip_runtime.h>
#include <math.h>
#include <algorithm>
#include <string.h>

#define NATOM 20000
#define NEIGH 600000
#define NWAVE 8
#define NSPH 16
// sortrec layout: [slot] = float4 { asfloat(j), sx, sy, sz }
// emb4 layout:    [atom*8 + w] = float4 { coeff, alpha, center, 0 }
// cart4 layout:   [atom] = float4 { x, y, z, 0 }

struct CFT {
  float v[6][7][7];  // [jseq][m1+3][m2+3], zero where invalid
};

__device__ __forceinline__ float silu_f(float x) { return x / (1.f + expf(-x)); }

// ---------------- Kernel 1: embedding MLP + packing + center-atom histogram ----------------
__global__ __launch_bounds__(256) void emb_hist_kernel(
    const float* __restrict__ species, const float* __restrict__ cart,
    const float* __restrict__ W1, const float* __restrict__ b1,
    const float* __restrict__ W2, const float* __restrict__ b2,
    const float* __restrict__ W3, const float* __restrict__ b3,
    float4* __restrict__ emb4, float4* __restrict__ cart4,
    const int* __restrict__ aidx, int* __restrict__ counts,
    int* __restrict__ rank_n)
{
  int t = blockIdx.x * 256 + threadIdx.x;
  if (t < NATOM) {
    float spv = species[t];
    float h1[16], h2[16], e24[24];
#pragma unroll
    for (int c = 0; c < 16; ++c) {
      float v = spv * W1[c] + b1[c];
      h1[c] = silu_f(v);
    }
#pragma unroll
    for (int d = 0; d < 16; ++d) {
      float v = b2[d];
#pragma unroll
      for (int c = 0; c < 16; ++c) v += h1[c] * W2[c * 16 + d];
      h2[d] = silu_f(v);
    }
#pragma unroll
    for (int e = 0; e < 24; ++e) {
      float v = b3[e];
#pragma unroll
      for (int c = 0; c < 16; ++c) v += h2[c] * W3[c * 24 + e];
      e24[e] = v;
    }
    float4* dst = emb4 + (size_t)t * 8;
#pragma unroll
    for (int w = 0; w < 8; ++w)
      dst[w] = make_float4(e24[w], e24[8 + w], e24[16 + w], 0.f);
    cart4[t] = make_float4(cart[t], cart[NATOM + t], cart[2 * NATOM + t], 0.f);
  }
  if (t < NEIGH) {
    int i = aidx[t];
    rank_n[t] = atomicAdd(&counts[i], 1);
  }
}

// ---------------- Kernel 2: exclusive scan (single workgroup) ----------------
__global__ __launch_bounds__(1024) void scan_kernel(
    const int* __restrict__ counts, int* __restrict__ offsets)
{
  __shared__ int psum[1024];
  int tid = threadIdx.x;
  const int PER = (NATOM + 1023) / 1024;  // 20
  int base = tid * PER;
  int s = 0;
  for (int q = 0; q < PER; ++q) {
    int idx = base + q;
    if (idx < NATOM) s += counts[idx];
  }
  psum[tid] = s;
  __syncthreads();
  for (int off = 1; off < 1024; off <<= 1) {
    int v = (tid >= off) ? psum[tid - off] : 0;
    __syncthreads();
    psum[tid] += v;
    __syncthreads();
  }
  int run = (tid == 0) ? 0 : psum[tid - 1];
  for (int q = 0; q < PER; ++q) {
    int idx = base + q;
    if (idx < NATOM) { offsets[idx] = run; run += counts[idx]; }
  }
  if (tid == 1023) offsets[NATOM] = run;
}

// ---------------- Kernel 3: sorted scatter of neighbor identities (no atomics) ----------------
__global__ __launch_bounds__(256) void rank_kernel(
    const int* __restrict__ aidx, const float* __restrict__ shifts,
    const int* __restrict__ offsets, const int* __restrict__ rank_n,
    float4* __restrict__ sortrec)
{
  int n = blockIdx.x * 256 + threadIdx.x;
  if (n >= NEIGH) return;
  int i = aidx[n];
  int slot = offsets[i] + rank_n[n];
  float4 r;
  r.x = __int_as_float(aidx[NEIGH + n]);
  r.y = shifts[n];
  r.z = shifts[NEIGH + n];
  r.w = shifts[2 * NEIGH + n];
  sortrec[slot] = r;
}

// ---------------- Kernel 4: fused compute + accumulate + Wigner contraction ----------------
// 32 lanes per atom: sub = q*4 + wp; q in [0,8) walks slots s0+q step 8,
// wp in [0,4) owns channels {wp, wp+4}. q-partials combined via shfl_xor
// butterfly over lane bits 2,3,4. Lane q==jj writes output row jj.
__global__ __launch_bounds__(256) void fused_kernel(
    const float4* __restrict__ cart4, const float4* __restrict__ sortrec,
    const float4* __restrict__ emb4, const int* __restrict__ offsets,
    float* __restrict__ out, CFT cf)
{
  int t = blockIdx.x * 256 + threadIdx.x;
  int a = t >> 5;         // grid is exact: NATOM*32/256
  int sub = t & 31;
  int wp = sub & 3;
  int q = sub >> 2;       // 0..7

  float4 ci = cart4[a];
  int s0 = offsets[a], s1 = offsets[a + 1];

  float acc0[NSPH], acc1[NSPH];
#pragma unroll
  for (int k = 0; k < NSPH; ++k) { acc0[k] = 0.f; acc1[k] = 0.f; }

  const float SQ2 = 1.41421356237309515f;
  for (int s = s0 + q; s < s1; s += 8) {
    float4 r = sortrec[s];
    int j = __float_as_int(r.x);
    float4 cj = cart4[j];
    float cx = cj.x - ci.x + r.y;
    float cy = cj.y - ci.y + r.z;
    float cz = cj.z - ci.z + r.w;
    float d2 = cx * cx + cy * cy + cz * cz;
    float inv = __frsqrt_rn(d2);
    float dist = d2 * inv;
    float x = cx * inv, y = cy * inv, z = cz * inv;

    float cc = __cosf(dist * 0.62831853071795864769f);
    float cut0 = (cc + 1.f) * 0.5f;
    float cut = cut0 * cut0 * cut0;

    float4 e0 = emb4[(size_t)j * 8 + wp];
    float4 e1 = emb4[(size_t)j * 8 + wp + 4];
    float sd0 = e0.y * (dist - e0.z);
    float av0 = cut * e0.x * __expf(-sd0 * sd0);
    float sd1 = e1.y * (dist - e1.z);
    float av1 = cut * e1.x * __expf(-sd1 * sd1);

    float r2 = x * x + y * y;
    float cp, sp;
    if (r2 > 0.f) { float ri = __frsqrt_rn(r2); cp = x * ri; sp = y * ri; }
    else          { cp = 1.f; sp = 0.f; }
    float c2 = cp * cp - sp * sp, s2 = 2.f * cp * sp;
    float c3 = c2 * cp - s2 * sp, s3 = s2 * cp + c2 * sp;

    float sz = sqrtf(fmaxf(1.f - z * z, 0.f));
    float P11 = -sz;
    float P22 = -3.f * sz * P11;
    float P33 = -5.f * sz * P22;
    float P10 = z;
    float P21 = 3.f * z * P11;
    float P32 = 5.f * z * P22;
    float P20 = (3.f * z * P10 - 1.f) * 0.5f;
    float P31 = (5.f * z * P21 - 3.f * P11) * 0.5f;
    float P30 = (5.f * z * P20 - 2.f * P10) * (1.f / 3.f);

    float sph[NSPH];
    sph[0]  = 0.28209479177387814f;
    sph[1]  = SQ2 * 0.3454941494713355f  * sp * P11;
    sph[2]  = 0.4886025119029199f * P10;
    sph[3]  = SQ2 * 0.3454941494713355f  * cp * P11;
    sph[4]  = SQ2 * 0.12875806734106326f * s2 * P22;
    sph[5]  = SQ2 * 0.25751613468212653f * sp * P21;
    sph[6]  = 0.6307831305050401f * P20;
    sph[7]  = SQ2 * 0.25751613468212653f * cp * P21;
    sph[8]  = SQ2 * 0.12875806734106326f * c2 * P22;
    sph[9]  = SQ2 * 0.027814921575518937f * s3 * P33;
    sph[10] = SQ2 * 0.06813236509555433f  * s2 * P32;
    sph[11] = SQ2 * 0.2154534560761003f   * sp * P31;
    sph[12] = 0.7463526651802308f * P30;
    sph[13] = SQ2 * 0.2154534560761003f   * cp * P31;
    sph[14] = SQ2 * 0.06813236509555433f  * c2 * P32;
    sph[15] = SQ2 * 0.027814921575518937f * c3 * P33;

#pragma unroll
    for (int k = 0; k < NSPH; ++k) {
      acc0[k] += sph[k] * av0;
      acc1[k] += sph[k] * av1;
    }
  }

  // combine the 8 q-partials (lane bits 2,3,4)
#pragma unroll
  for (int k = 0; k < NSPH; ++k) {
    acc0[k] += __shfl_xor(acc0[k], 4);
    acc0[k] += __shfl_xor(acc0[k], 8);
    acc0[k] += __shfl_xor(acc0[k], 16);
    acc1[k] += __shfl_xor(acc1[k], 4);
    acc1[k] += __shfl_xor(acc1[k], 8);
    acc1[k] += __shfl_xor(acc1[k], 16);
  }

  // Wigner contraction, fully unrolled static indices; lane q writes jj==q.
  constexpr int J0s[6] = {1, 1, 2, 2, 1, 3};
  constexpr int J1s[6] = {1, 1, 2, 2, 2, 3};
  constexpr int J2s[6] = {0, 2, 2, 0, 3, 2};
#pragma unroll
  for (int jj = 0; jj < 6; ++jj) {
    const int J0 = J0s[jj], J1 = J1s[jj], J2 = J2s[jj];
    const int n0 = J0 * (J0 + 1), n1 = J1 * (J1 + 1), n2 = J2 * (J2 + 1);
    float dj0 = 0.f, dj1 = 0.f;
#pragma unroll
    for (int m1 = -3; m1 <= 3; ++m1) {
      if (m1 < -J0 || m1 > J0) continue;
#pragma unroll
      for (int m2 = -3; m2 <= 3; ++m2) {
        if (m2 < -J1 || m2 > J1) continue;
        const int m3 = -m1 - m2;
        if (m3 < -J2 || m3 > J2) continue;
        const float w3 = cf.v[jj][m1 + 3][m2 + 3];
        dj0 += acc0[n0 + m1] * acc0[n1 + m2] * acc0[n2 + m3] * w3;
        dj1 += acc1[n0 + m1] * acc1[n1 + m2] * acc1[n2 + m3] * w3;
      }
    }
    if (q == jj) {
      out[((size_t)jj * NATOM + a) * 8 + wp]     = dj0;
      out[((size_t)jj * NATOM + a) * 8 + wp + 4] = dj1;
    }
  }
}

// ---------------- host: exact Wigner 3j (Racah) ----------------
static double dfact(int n) { double r = 1.0; for (int i = 2; i <= n; ++i) r *= i; return r; }
static double wig3j(int j1, int j2, int j3, int m1, int m2, int m3) {
  if (m1 + m2 + m3 != 0) return 0.0;
  double pre = sqrt(dfact(j1 + j2 - j3) * dfact(j1 - j2 + j3) * dfact(-j1 + j2 + j3)
                    / dfact(j1 + j2 + j3 + 1)
                    * dfact(j1 + m1) * dfact(j1 - m1) * dfact(j2 + m2) * dfact(j2 - m2)
                    * dfact(j3 + m3) * dfact(j3 - m3));
  int tmin = std::max(0, std::max(j2 - j3 - m1, j1 - j3 + m2));
  int tmax = std::min(j1 + j2 - j3, std::min(j1 - m1, j2 + m2));
  double s = 0.0;
  for (int t = tmin; t <= tmax; ++t)
    s += ((t & 1) ? -1.0 : 1.0) /
         (dfact(t) * dfact(j3 - j2 + m1 + t) * dfact(j3 - j1 - m2 + t) *
          dfact(j1 + j2 - j3 - t) * dfact(j1 - m1 - t) * dfact(j2 + m2 - t));
  int e = j1 - j2 - m3;
  double sgn = ((e % 2) != 0) ? -1.0 : 1.0;
  return sgn * pre * s;
}

extern "C" void kernel_launch(void* const* d_in, const int* in_sizes, int n_in,
                              void* d_out, int out_size, void* d_ws, size_t ws_size,
                              hipStream_t stream)
{
  const float* cart    = (const float*)d_in[0];
  const int*   aidx    = (const int*)d_in[1];
  const float* shifts  = (const float*)d_in[2];
  const float* species = (const float*)d_in[3];
  const float* W1 = (const float*)d_in[4];
  const float* b1 = (const float*)d_in[5];
  const float* W2 = (const float*)d_in[6];
  const float* b2 = (const float*)d_in[7];
  const float* W3 = (const float*)d_in[8];
  const float* b3 = (const float*)d_in[9];
  float* out = (float*)d_out;

  // ws layout: sortrec | emb4 | cart4 | counts | rank_n | offsets
  float4* sortrec = (float4*)d_ws;                        // NEIGH float4
  float4* emb4    = sortrec + NEIGH;                      // NATOM*8 float4
  float4* cart4   = emb4 + (size_t)NATOM * 8;             // NATOM float4
  int*    counts  = (int*)(cart4 + NATOM);                // NATOM
  int*    rank_n  = counts + NATOM;                       // NEIGH
  int*    offsets = rank_n + NEIGH;                       // NATOM+1

  // Dense Wigner-3j coefficient cube (deterministic, input-independent)
  static const int JS[6][3] = {{1,1,0},{1,1,2},{2,2,2},{2,2,0},{1,2,3},{3,3,2}};
  CFT cf;
  memset(&cf, 0, sizeof(cf));
  for (int j = 0; j < 6; ++j) {
    int J0 = JS[j][0], J1 = JS[j][1], J2 = JS[j][2];
    for (int m1 = -J0; m1 <= J0; ++m1)
      for (int m2 = std::max(-J2 - m1, -J1); m2 <= std::min(J2 - m1, J1); ++m2) {
        int m3 = -m1 - m2;
        cf.v[j][m1 + 3][m2 + 3] = (float)wig3j(J0, J1, J2, m1, m2, m3);
      }
  }

  hipMemsetAsync(counts, 0, (size_t)NATOM * sizeof(int), stream);
  emb_hist_kernel<<<(NEIGH + 255) / 256, 256, 0, stream>>>(
      species, cart, W1, b1, W2, b2, W3, b3, emb4, cart4, aidx, counts, rank_n);
  scan_kernel<<<1, 1024, 0, stream>>>(counts, offsets);
  rank_kernel<<<(NEIGH + 255) / 256, 256, 0, stream>>>(aidx, shifts, offsets, rank_n, sortrec);
  fused_kernel<<<(NATOM * 32) / 256, 256, 0, stream>>>(
      cart4, sortrec, emb4, offsets, out, cf);
}

// Round 6
// 77.896 us; speedup vs baseline: 51.3326x; 1.3440x over previous
//
#include <hip/hip_runtime.h>
#include <math.h>
#include <algorithm>
#include <string.h>

#define NATOM 20000
#define NEIGH 600000
#define NWAVE 8
#define NSPH 16
#define CAP 96   // fixed bucket capacity per atom (mean occupancy 30, P(>=96) ~ 1e-20)
// sortrec layout: [atom*CAP + rank] = float4 { asfloat(j), sx, sy, sz }
// emb4 layout:    [atom*8 + w] = float4 { coeff, alpha, center, 0 }
// cart4 layout:   [atom] = float4 { x, y, z, 0 }

struct CFT {
  float v[6][7][7];  // [jseq][m1+3][m2+3], zero where invalid
};

__device__ __forceinline__ float silu_f(float x) { return x / (1.f + expf(-x)); }

// ---------------- Kernel 0: zero the per-atom counters (replaces 43us runtime fill) ----------------
__global__ __launch_bounds__(256) void zero_kernel(int* __restrict__ counts)
{
  int t = blockIdx.x * 256 + threadIdx.x;
  if (t < NATOM) counts[t] = 0;
}

// ---------------- Kernel 1: embedding MLP + packing + bucket scatter of neighbors ----------------
__global__ __launch_bounds__(256) void emb_scatter_kernel(
    const float* __restrict__ species, const float* __restrict__ cart,
    const float* __restrict__ W1, const float* __restrict__ b1,
    const float* __restrict__ W2, const float* __restrict__ b2,
    const float* __restrict__ W3, const float* __restrict__ b3,
    float4* __restrict__ emb4, float4* __restrict__ cart4,
    const int* __restrict__ aidx, const float* __restrict__ shifts,
    int* __restrict__ counts, float4* __restrict__ sortrec)
{
  int t = blockIdx.x * 256 + threadIdx.x;
  if (t < NATOM) {
    float spv = species[t];
    float h1[16], h2[16], e24[24];
#pragma unroll
    for (int c = 0; c < 16; ++c) {
      float v = spv * W1[c] + b1[c];
      h1[c] = silu_f(v);
    }
#pragma unroll
    for (int d = 0; d < 16; ++d) {
      float v = b2[d];
#pragma unroll
      for (int c = 0; c < 16; ++c) v += h1[c] * W2[c * 16 + d];
      h2[d] = silu_f(v);
    }
#pragma unroll
    for (int e = 0; e < 24; ++e) {
      float v = b3[e];
#pragma unroll
      for (int c = 0; c < 16; ++c) v += h2[c] * W3[c * 24 + e];
      e24[e] = v;
    }
    float4* dst = emb4 + (size_t)t * 8;
#pragma unroll
    for (int w = 0; w < 8; ++w)
      dst[w] = make_float4(e24[w], e24[8 + w], e24[16 + w], 0.f);
    cart4[t] = make_float4(cart[t], cart[NATOM + t], cart[2 * NATOM + t], 0.f);
  }
  if (t < NEIGH) {
    int i = aidx[t];
    int rank = atomicAdd(&counts[i], 1);
    float4 r;
    r.x = __int_as_float(aidx[NEIGH + t]);
    r.y = shifts[t];
    r.z = shifts[NEIGH + t];
    r.w = shifts[2 * NEIGH + t];
    sortrec[(size_t)i * CAP + rank] = r;
  }
}

// ---------------- Kernel 2: fused compute + accumulate + Wigner contraction ----------------
// 32 lanes per atom: sub = q*4 + wp; q in [0,8) walks slots base+q step 8,
// wp in [0,4) owns channels {wp, wp+4}. q-partials combined via shfl_xor
// butterfly over lane bits 2,3,4. Lane q==jj writes output row jj.
__global__ __launch_bounds__(256) void fused_kernel(
    const float4* __restrict__ cart4, const float4* __restrict__ sortrec,
    const float4* __restrict__ emb4, const int* __restrict__ counts,
    float* __restrict__ out, CFT cf)
{
  int t = blockIdx.x * 256 + threadIdx.x;
  int a = t >> 5;         // grid is exact: NATOM*32/256
  int sub = t & 31;
  int wp = sub & 3;
  int q = sub >> 2;       // 0..7

  float4 ci = cart4[a];
  int s0 = a * CAP;
  int s1 = s0 + counts[a];

  float acc0[NSPH], acc1[NSPH];
#pragma unroll
  for (int k = 0; k < NSPH; ++k) { acc0[k] = 0.f; acc1[k] = 0.f; }

  const float SQ2 = 1.41421356237309515f;
  for (int s = s0 + q; s < s1; s += 8) {
    float4 r = sortrec[s];
    int j = __float_as_int(r.x);
    float4 cj = cart4[j];
    float cx = cj.x - ci.x + r.y;
    float cy = cj.y - ci.y + r.z;
    float cz = cj.z - ci.z + r.w;
    float d2 = cx * cx + cy * cy + cz * cz;
    float inv = __frsqrt_rn(d2);
    float dist = d2 * inv;
    float x = cx * inv, y = cy * inv, z = cz * inv;

    float cc = __cosf(dist * 0.62831853071795864769f);
    float cut0 = (cc + 1.f) * 0.5f;
    float cut = cut0 * cut0 * cut0;

    float4 e0 = emb4[(size_t)j * 8 + wp];
    float4 e1 = emb4[(size_t)j * 8 + wp + 4];
    float sd0 = e0.y * (dist - e0.z);
    float av0 = cut * e0.x * __expf(-sd0 * sd0);
    float sd1 = e1.y * (dist - e1.z);
    float av1 = cut * e1.x * __expf(-sd1 * sd1);

    float r2 = x * x + y * y;
    float ri = __frsqrt_rn(fmaxf(r2, 1e-30f));
    float cp = x * ri, sp = y * ri;
    float c2 = cp * cp - sp * sp, s2 = 2.f * cp * sp;
    float c3 = c2 * cp - s2 * sp, s3 = s2 * cp + c2 * sp;

    float sz = sqrtf(fmaxf(1.f - z * z, 0.f));
    float P11 = -sz;
    float P22 = -3.f * sz * P11;
    float P33 = -5.f * sz * P22;
    float P10 = z;
    float P21 = 3.f * z * P11;
    float P32 = 5.f * z * P22;
    float P20 = (3.f * z * P10 - 1.f) * 0.5f;
    float P31 = (5.f * z * P21 - 3.f * P11) * 0.5f;
    float P30 = (5.f * z * P20 - 2.f * P10) * (1.f / 3.f);

    float sph[NSPH];
    sph[0]  = 0.28209479177387814f;
    sph[1]  = SQ2 * 0.3454941494713355f  * sp * P11;
    sph[2]  = 0.4886025119029199f * P10;
    sph[3]  = SQ2 * 0.3454941494713355f  * cp * P11;
    sph[4]  = SQ2 * 0.12875806734106326f * s2 * P22;
    sph[5]  = SQ2 * 0.25751613468212653f * sp * P21;
    sph[6]  = 0.6307831305050401f * P20;
    sph[7]  = SQ2 * 0.25751613468212653f * cp * P21;
    sph[8]  = SQ2 * 0.12875806734106326f * c2 * P22;
    sph[9]  = SQ2 * 0.027814921575518937f * s3 * P33;
    sph[10] = SQ2 * 0.06813236509555433f  * s2 * P32;
    sph[11] = SQ2 * 0.2154534560761003f   * sp * P31;
    sph[12] = 0.7463526651802308f * P30;
    sph[13] = SQ2 * 0.2154534560761003f   * cp * P31;
    sph[14] = SQ2 * 0.06813236509555433f  * c2 * P32;
    sph[15] = SQ2 * 0.027814921575518937f * c3 * P33;

#pragma unroll
    for (int k = 0; k < NSPH; ++k) {
      acc0[k] += sph[k] * av0;
      acc1[k] += sph[k] * av1;
    }
  }

  // combine the 8 q-partials (lane bits 2,3,4)
#pragma unroll
  for (int k = 0; k < NSPH; ++k) {
    acc0[k] += __shfl_xor(acc0[k], 4);
    acc0[k] += __shfl_xor(acc0[k], 8);
    acc0[k] += __shfl_xor(acc0[k], 16);
    acc1[k] += __shfl_xor(acc1[k], 4);
    acc1[k] += __shfl_xor(acc1[k], 8);
    acc1[k] += __shfl_xor(acc1[k], 16);
  }

  // Wigner contraction, fully unrolled static indices; lane q writes jj==q.
  constexpr int J0s[6] = {1, 1, 2, 2, 1, 3};
  constexpr int J1s[6] = {1, 1, 2, 2, 2, 3};
  constexpr int J2s[6] = {0, 2, 2, 0, 3, 2};
#pragma unroll
  for (int jj = 0; jj < 6; ++jj) {
    const int J0 = J0s[jj], J1 = J1s[jj], J2 = J2s[jj];
    const int n0 = J0 * (J0 + 1), n1 = J1 * (J1 + 1), n2 = J2 * (J2 + 1);
    float dj0 = 0.f, dj1 = 0.f;
#pragma unroll
    for (int m1 = -3; m1 <= 3; ++m1) {
      if (m1 < -J0 || m1 > J0) continue;
#pragma unroll
      for (int m2 = -3; m2 <= 3; ++m2) {
        if (m2 < -J1 || m2 > J1) continue;
        const int m3 = -m1 - m2;
        if (m3 < -J2 || m3 > J2) continue;
        const float w3 = cf.v[jj][m1 + 3][m2 + 3];
        dj0 += acc0[n0 + m1] * acc0[n1 + m2] * acc0[n2 + m3] * w3;
        dj1 += acc1[n0 + m1] * acc1[n1 + m2] * acc1[n2 + m3] * w3;
      }
    }
    if (q == jj) {
      out[((size_t)jj * NATOM + a) * 8 + wp]     = dj0;
      out[((size_t)jj * NATOM + a) * 8 + wp + 4] = dj1;
    }
  }
}

// ---------------- host: exact Wigner 3j (Racah) ----------------
static double dfact(int n) { double r = 1.0; for (int i = 2; i <= n; ++i) r *= i; return r; }
static double wig3j(int j1, int j2, int j3, int m1, int m2, int m3) {
  if (m1 + m2 + m3 != 0) return 0.0;
  double pre = sqrt(dfact(j1 + j2 - j3) * dfact(j1 - j2 + j3) * dfact(-j1 + j2 + j3)
                    / dfact(j1 + j2 + j3 + 1)
                    * dfact(j1 + m1) * dfact(j1 - m1) * dfact(j2 + m2) * dfact(j2 - m2)
                    * dfact(j3 + m3) * dfact(j3 - m3));
  int tmin = std::max(0, std::max(j2 - j3 - m1, j1 - j3 + m2));
  int tmax = std::min(j1 + j2 - j3, std::min(j1 - m1, j2 + m2));
  double s = 0.0;
  for (int t = tmin; t <= tmax; ++t)
    s += ((t & 1) ? -1.0 : 1.0) /
         (dfact(t) * dfact(j3 - j2 + m1 + t) * dfact(j3 - j1 - m2 + t) *
          dfact(j1 + j2 - j3 - t) * dfact(j1 - m1 - t) * dfact(j2 + m2 - t));
  int e = j1 - j2 - m3;
  double sgn = ((e % 2) != 0) ? -1.0 : 1.0;
  return sgn * pre * s;
}

extern "C" void kernel_launch(void* const* d_in, const int* in_sizes, int n_in,
                              void* d_out, int out_size, void* d_ws, size_t ws_size,
                              hipStream_t stream)
{
  const float* cart    = (const float*)d_in[0];
  const int*   aidx    = (const int*)d_in[1];
  const float* shifts  = (const float*)d_in[2];
  const float* species = (const float*)d_in[3];
  const float* W1 = (const float*)d_in[4];
  const float* b1 = (const float*)d_in[5];
  const float* W2 = (const float*)d_in[6];
  const float* b2 = (const float*)d_in[7];
  const float* W3 = (const float*)d_in[8];
  const float* b3 = (const float*)d_in[9];
  float* out = (float*)d_out;

  // ws layout: sortrec buckets | emb4 | cart4 | counts   (~30.7 + 2.56 + 0.32 + 0.08 MB)
  float4* sortrec = (float4*)d_ws;                        // NATOM*CAP float4
  float4* emb4    = sortrec + (size_t)NATOM * CAP;        // NATOM*8 float4
  float4* cart4   = emb4 + (size_t)NATOM * 8;             // NATOM float4
  int*    counts  = (int*)(cart4 + NATOM);                // NATOM

  // Dense Wigner-3j coefficient cube (deterministic, input-independent)
  static const int JS[6][3] = {{1,1,0},{1,1,2},{2,2,2},{2,2,0},{1,2,3},{3,3,2}};
  CFT cf;
  memset(&cf, 0, sizeof(cf));
  for (int j = 0; j < 6; ++j) {
    int J0 = JS[j][0], J1 = JS[j][1], J2 = JS[j][2];
    for (int m1 = -J0; m1 <= J0; ++m1)
      for (int m2 = std::max(-J2 - m1, -J1); m2 <= std::min(J2 - m1, J1); ++m2) {
        int m3 = -m1 - m2;
        cf.v[j][m1 + 3][m2 + 3] = (float)wig3j(J0, J1, J2, m1, m2, m3);
      }
  }

  zero_kernel<<<(NATOM + 255) / 256, 256, 0, stream>>>(counts);
  emb_scatter_kernel<<<(NEIGH + 255) / 256, 256, 0, stream>>>(
      species, cart, W1, b1, W2, b2, W3, b3, emb4, cart4, aidx, shifts, counts, sortrec);
  fused_kernel<<<(NATOM * 32) / 256, 256, 0, stream>>>(
      cart4, sortrec, emb4, counts, out, cf);
}